// Round 7
// baseline (716.921 us; speedup 1.0000x reference)
//
#include <hip/hip_runtime.h>
#include <cstdint>
#include <cstddef>

#define BB 64
#define TT 512
#define DD 1024
#define NTAG 64
#define SCORES_ELEMS (BB * TT * NTAG)      // 2097152
#define TAGS_OFF SCORES_ELEMS              // 2097152
#define LOSS_OFF (SCORES_ELEMS + BB * TT)  // 2130920

__device__ __forceinline__ float rl(float v, int i) {
  return __int_as_float(__builtin_amdgcn_readlane(__float_as_int(v), i));
}

// ---------------- DPP wave64 reductions ----------------
__device__ __forceinline__ float dpp_red_max(float v) {
  int x;
  x = __builtin_amdgcn_update_dpp(__float_as_int(v), __float_as_int(v), 0x111, 0xf, 0xf, false);
  v = fmaxf(v, __int_as_float(x));
  x = __builtin_amdgcn_update_dpp(__float_as_int(v), __float_as_int(v), 0x112, 0xf, 0xf, false);
  v = fmaxf(v, __int_as_float(x));
  x = __builtin_amdgcn_update_dpp(__float_as_int(v), __float_as_int(v), 0x114, 0xf, 0xf, false);
  v = fmaxf(v, __int_as_float(x));
  x = __builtin_amdgcn_update_dpp(__float_as_int(v), __float_as_int(v), 0x118, 0xf, 0xf, false);
  v = fmaxf(v, __int_as_float(x));
  x = __builtin_amdgcn_update_dpp(__float_as_int(v), __float_as_int(v), 0x142, 0xa, 0xf, false);
  v = fmaxf(v, __int_as_float(x));
  x = __builtin_amdgcn_update_dpp(__float_as_int(v), __float_as_int(v), 0x143, 0xc, 0xf, false);
  v = fmaxf(v, __int_as_float(x));
  return __int_as_float(__builtin_amdgcn_readlane(__float_as_int(v), 63));
}

__device__ __forceinline__ float dpp_red_sum(float v) {
  int x;
  x = __builtin_amdgcn_update_dpp(__float_as_int(v), __float_as_int(v), 0x111, 0xf, 0xf, false);
  v = v + __int_as_float(x);
  x = __builtin_amdgcn_update_dpp(__float_as_int(v), __float_as_int(v), 0x112, 0xf, 0xf, false);
  v = v + __int_as_float(x);
  x = __builtin_amdgcn_update_dpp(__float_as_int(v), __float_as_int(v), 0x114, 0xf, 0xf, false);
  v = v + __int_as_float(x);
  x = __builtin_amdgcn_update_dpp(__float_as_int(v), __float_as_int(v), 0x118, 0xf, 0xf, false);
  v = v + __int_as_float(x);
  x = __builtin_amdgcn_update_dpp(__float_as_int(v), __float_as_int(v), 0x142, 0xa, 0xf, false);
  v = v + __int_as_float(x);
  x = __builtin_amdgcn_update_dpp(__float_as_int(v), __float_as_int(v), 0x143, 0xc, 0xf, false);
  v = v + __int_as_float(x);
  return __int_as_float(__builtin_amdgcn_readlane(__float_as_int(v), 63));
}

// ---------------- Kernel 1: scores = (X @ W + b) * mask ----------------
// 512 blocks x 256 thr. Block tile 64x64; 4 waves split K (256 each, no
// main-loop barriers). 8x8 acc/lane: 64 FMA per 2 ds_read_b128 (VALU-bound
// ratio). W rolling-prefetched from global (L2-resident); X staged in LDS.
__global__ __launch_bounds__(256, 4) void gemm_scores(
    const float* __restrict__ X, const int* __restrict__ mask,
    const float* __restrict__ W, const float* __restrict__ bias,
    float* __restrict__ scores) {
  __shared__ float smem[8192];  // [0,4096): X stage 4 waves x 1024; [4096,8192): psum 64x64
  const int tid = threadIdx.x;
  const int lane = tid & 63;
  const int wv = tid >> 6;
  const int row0 = blockIdx.x * 64;
  const int kbase = wv * 256;
  float* psum = smem + 4096;

  {  // zero psum: 4096 floats / 256 thr = 16 each
    const float4 z4 = make_float4(0.f, 0.f, 0.f, 0.f);
#pragma unroll
    for (int g = 0; g < 4; ++g)
      *reinterpret_cast<float4*>(&psum[tid * 16 + g * 4]) = z4;
  }
  __syncthreads();

  float* smx = smem + wv * 1024;  // [16 k][64 rows]
  const int lr = lane & 7;        // row-group (8 rows)
  const int lc8 = (lane >> 3) * 8;  // col base

  float acc[8][8];
#pragma unroll
  for (int i = 0; i < 8; ++i)
#pragma unroll
    for (int j = 0; j < 8; ++j) acc[i][j] = 0.f;

  const float* Xrow = X + (size_t)(row0 + lane) * DD + kbase;  // lane's staging row
  const float* Wb = W + (size_t)kbase * NTAG;

  float4 px[4];
#pragma unroll
  for (int p = 0; p < 4; ++p)
    px[p] = *reinterpret_cast<const float4*>(Xrow + p * 4);

  for (int c = 0; c < 16; ++c) {
    // stage X chunk [16k][64rows], transposed scalar writes (conflict-free)
#pragma unroll
    for (int p = 0; p < 4; ++p) {
      smx[(p * 4 + 0) * 64 + lane] = px[p].x;
      smx[(p * 4 + 1) * 64 + lane] = px[p].y;
      smx[(p * 4 + 2) * 64 + lane] = px[p].z;
      smx[(p * 4 + 3) * 64 + lane] = px[p].w;
    }
    const int cn = (c < 15) ? (c + 1) : 0;  // dummy reload last iter
#pragma unroll
    for (int p = 0; p < 4; ++p)
      px[p] = *reinterpret_cast<const float4*>(Xrow + cn * 16 + p * 4);

    const float* Wc = Wb + c * 1024;  // 16 k x 64 cols
    float4 wa = *reinterpret_cast<const float4*>(Wc + lc8);
    float4 wb = *reinterpret_cast<const float4*>(Wc + lc8 + 4);
#pragma unroll
    for (int k = 0; k < 16; ++k) {
      const int kn = (k + 1) & 15;  // rolling W prefetch (k=15 -> dummy k=0)
      const float4 wan = *reinterpret_cast<const float4*>(Wc + kn * 64 + lc8);
      const float4 wbn = *reinterpret_cast<const float4*>(Wc + kn * 64 + lc8 + 4);
      const float4 xa = *reinterpret_cast<const float4*>(&smx[k * 64 + lr * 8]);
      const float4 xb = *reinterpret_cast<const float4*>(&smx[k * 64 + lr * 8 + 4]);
      const float x0 = xa.x, x1 = xa.y, x2 = xa.z, x3 = xa.w;
      const float x4 = xb.x, x5 = xb.y, x6 = xb.z, x7 = xb.w;
      const float q0 = wa.x, q1 = wa.y, q2 = wa.z, q3 = wa.w;
      const float q4 = wb.x, q5 = wb.y, q6 = wb.z, q7 = wb.w;
#define ROW(i, xi)                                                          \
  acc[i][0] = fmaf(xi, q0, acc[i][0]); acc[i][1] = fmaf(xi, q1, acc[i][1]); \
  acc[i][2] = fmaf(xi, q2, acc[i][2]); acc[i][3] = fmaf(xi, q3, acc[i][3]); \
  acc[i][4] = fmaf(xi, q4, acc[i][4]); acc[i][5] = fmaf(xi, q5, acc[i][5]); \
  acc[i][6] = fmaf(xi, q6, acc[i][6]); acc[i][7] = fmaf(xi, q7, acc[i][7]);
      ROW(0, x0) ROW(1, x1) ROW(2, x2) ROW(3, x3)
      ROW(4, x4) ROW(5, x5) ROW(6, x6) ROW(7, x7)
#undef ROW
      wa = wan; wb = wbn;
    }
  }

  // combine wave partials; stagger j by lr (2 lanes/bank: free)
#pragma unroll
  for (int i = 0; i < 8; ++i) {
    const int row = lr * 8 + i;
#pragma unroll
    for (int j = 0; j < 8; ++j) {
      const int jj = (j + lr) & 7;
      atomicAdd(&psum[row * 64 + lc8 + jj], acc[i][jj]);
    }
  }
  __syncthreads();

  // epilogue: 16 floats/thread, all within one 64-col row
  const int f = tid * 16;
  const int row = f >> 6;
  const float mf = (float)mask[row0 + row];
#pragma unroll
  for (int g = 0; g < 4; ++g) {
    const int idx = f + g * 4;
    const int col = idx & 63;
    const float4 p = *reinterpret_cast<float4*>(&psum[idx]);
    const float4 b4 = *reinterpret_cast<const float4*>(&bias[col]);
    float4 o;
    o.x = (p.x + b4.x) * mf;
    o.y = (p.y + b4.y) * mf;
    o.z = (p.z + b4.z) * mf;
    o.w = (p.w + b4.w) * mf;
    *reinterpret_cast<float4*>(&scores[(size_t)(row0 + row) * 64 + col]) = o;
  }
}

// ---------------- Kernel 2: CRF forward, 4 waves per batch ----------------
// grid 128 x 256. Blocks [0,64): viterbi fwd + in-LDS backpointers + chase.
// Blocks [64,128): z-space log-partition + gold. Each wave owns 16 source
// tags; partials combined via double-buffered LDS + 1 barrier/step. Alpha/z
// state replicated in all 4 waves (identical deterministic ops).
__global__ __launch_bounds__(256) void crf_forward(
    const float* __restrict__ scores, const int* __restrict__ mask,
    const int* __restrict__ labels, const float* __restrict__ trans,
    const float* __restrict__ startv, const float* __restrict__ endv,
    float* __restrict__ out_tags, float* __restrict__ ws_loss) {
  __shared__ float pval[2][256];
  __shared__ int pidx[2][256];
  __shared__ unsigned char bp_lds[(TT - 1) * NTAG];  // 32704 B
  __shared__ unsigned char tagb[TT];
  __shared__ int mk[TT];
  const int tid = threadIdx.x;
  const int lane = tid & 63;
  const int wv = tid >> 6;
  const int role = blockIdx.x >> 6;
  const int b = blockIdx.x & 63;
  const float* sc = scores + (size_t)b * TT * NTAG;
  const int* maskb = mask + b * TT;
  const int ib = wv * 16;

  if (role == 0) {
    // ---------------- Viterbi forward + backpointers ----------------
    for (int t = tid; t < TT; t += 256) mk[t] = maskb[t];
    float tc[16];
#pragma unroll
    for (int q = 0; q < 16; ++q) tc[q] = trans[(size_t)(ib + q) * NTAG + lane];
    float valpha = startv[lane] + sc[lane];

    float e0 = sc[1 * NTAG + lane], e1 = sc[2 * NTAG + lane];
    float e2 = sc[3 * NTAG + lane], e3 = sc[4 * NTAG + lane];
    int k0 = maskb[1], k1 = maskb[2], k2 = maskb[3], k3 = maskb[4];
    int buf = 0;

    for (int t = 1; t < TT; ++t) {
      const float emit = e0;
      const int m = k0;
      const int tp = (t + 4 < TT) ? (t + 4) : (TT - 1);
      e0 = e1; e1 = e2; e2 = e3;
      e3 = sc[(size_t)tp * NTAG + lane];
      k0 = k1; k1 = k2; k2 = k3;
      k3 = maskb[tp];

      // per-wave 16-candidate max+argmax (first-index ties: left wins)
      float cv[16];
#pragma unroll
      for (int q = 0; q < 16; ++q) cv[q] = rl(valpha, ib + q) + tc[q];
      float v8[8]; int i8[8];
#pragma unroll
      for (int q = 0; q < 8; ++q) {
        const bool g = cv[2 * q] >= cv[2 * q + 1];
        v8[q] = g ? cv[2 * q] : cv[2 * q + 1];
        i8[q] = g ? (2 * q) : (2 * q + 1);
      }
      float v4[4]; int i4[4];
#pragma unroll
      for (int q = 0; q < 4; ++q) {
        const bool g = v8[2 * q] >= v8[2 * q + 1];
        v4[q] = g ? v8[2 * q] : v8[2 * q + 1];
        i4[q] = g ? i8[2 * q] : i8[2 * q + 1];
      }
      const bool ga = v4[0] >= v4[1];
      const float va = ga ? v4[0] : v4[1];
      const int ia = ga ? i4[0] : i4[1];
      const bool gb = v4[2] >= v4[3];
      const float vb = gb ? v4[2] : v4[3];
      const int ibx = gb ? i4[2] : i4[3];
      const bool gw = va >= vb;
      pval[buf][wv * 64 + lane] = gw ? va : vb;
      pidx[buf][wv * 64 + lane] = ib + (gw ? ia : ibx);
      __syncthreads();

      const float w0v = pval[buf][lane],       w1v = pval[buf][64 + lane];
      const float w2v = pval[buf][128 + lane], w3v = pval[buf][192 + lane];
      const int w0i = pidx[buf][lane],       w1i = pidx[buf][64 + lane];
      const int w2i = pidx[buf][128 + lane], w3i = pidx[buf][192 + lane];
      const bool g01 = w0v >= w1v;
      const float m01 = g01 ? w0v : w1v; const int j01 = g01 ? w0i : w1i;
      const bool g23 = w2v >= w3v;
      const float m23 = g23 ? w2v : w3v; const int j23 = g23 ? w2i : w3i;
      const bool gf = m01 >= m23;
      const float best = gf ? m01 : m23;
      const int bpi = gf ? j01 : j23;

      if (wv == 0) bp_lds[(t - 1) * NTAG + lane] = (unsigned char)bpi;
      valpha = m ? (best + emit) : valpha;
      buf ^= 1;
    }

    // last tag (replicated; wave 0 acts)
    const float fin = valpha + endv[lane];
    const float mx = dpp_red_max(fin);
    const int jlast = (int)__builtin_ctzll(__ballot(fin == mx));
    if (tid == 0) {
      int jcur = jlast;
      tagb[TT - 1] = (unsigned char)jcur;
      for (int s = TT - 2; s >= 0; --s) {
        if (mk[s + 1]) jcur = bp_lds[s * NTAG + jcur];
        tagb[s] = (unsigned char)jcur;
      }
    }
    __syncthreads();
    for (int t = tid; t < TT; t += 256)
      out_tags[b * TT + t] = (float)(mk[t] ? (int)tagb[t] : 0);
  } else {
    // ---------------- log-partition (z-space) + gold ----------------
    float ec[16];
#pragma unroll
    for (int q = 0; q < 16; ++q) ec[q] = expf(trans[(size_t)(ib + q) * NTAG + lane]);

    const float alpha0 = startv[lane] + sc[lane];
    const float M0 = dpp_red_max(alpha0);
    float z = expf(alpha0 - M0);  // z = exp(alpha - C), replicated per wave
    float C = M0;

    float e0 = sc[1 * NTAG + lane], e1 = sc[2 * NTAG + lane];
    float e2 = sc[3 * NTAG + lane], e3 = sc[4 * NTAG + lane];
    int k0 = maskb[1], k1 = maskb[2], k2 = maskb[3], k3 = maskb[4];
    float pe = expf(e0);
    int buf = 0;

    for (int t = 1; t < TT; ++t) {
      const float pec = pe;
      const int m = k0;
      const int tp = (t + 4 < TT) ? (t + 4) : (TT - 1);
      e0 = e1; e1 = e2; e2 = e3;
      e3 = sc[(size_t)tp * NTAG + lane];
      k0 = k1; k1 = k2; k2 = k3;
      k3 = maskb[tp];
      pe = expf(e0);  // off critical path

      float s0 = 0.f, s1 = 0.f, s2 = 0.f, s3 = 0.f;
#pragma unroll
      for (int q = 0; q < 16; q += 4) {
        s0 = fmaf(rl(z, ib + q + 0), ec[q + 0], s0);
        s1 = fmaf(rl(z, ib + q + 1), ec[q + 1], s1);
        s2 = fmaf(rl(z, ib + q + 2), ec[q + 2], s2);
        s3 = fmaf(rl(z, ib + q + 3), ec[q + 3], s3);
      }
      pval[buf][wv * 64 + lane] = (s0 + s1) + (s2 + s3);
      __syncthreads();
      const float inner = (pval[buf][lane] + pval[buf][64 + lane]) +
                          (pval[buf][128 + lane] + pval[buf][192 + lane]);
      z = m ? (inner * pec) : z;
      buf ^= 1;

      if ((t & 7) == 0) {  // renormalize (replicated identically per wave)
        const float s = dpp_red_sum(z);
        const float r = __builtin_amdgcn_rcpf(s);
        z *= r;
        C += logf(s);
      }
    }

    if (wv == 0) {
      const float av = logf(z) + C;
      const float fv = av + endv[lane];
      const float M2 = dpp_red_max(fv);
      const float sSum = dpp_red_sum(expf(fv - M2));
      const float log_z = logf(sSum) + M2;

      float g = 0.f, msumf = 0.f;
      for (int t = lane; t < TT; t += 64) {
        const int lab = labels[b * TT + t];
        const float mf = (float)maskb[t];
        msumf += mf;
        g += sc[(size_t)t * NTAG + lab] * mf;
        if (t >= 1) {
          const int labp = labels[b * TT + t - 1];
          g += trans[(size_t)labp * NTAG + lab] * mf;
        }
      }
      g = dpp_red_sum(g);
      const float msum = dpp_red_sum(msumf);
      const int last_idx = (int)msum - 1;
      g += startv[labels[b * TT]] + endv[labels[b * TT + last_idx]];
      if (lane == 0) ws_loss[b] = log_z - g;
    }
  }
}

// ---------------- Kernel 3: loss = mean(log_z - gold) ----------------
__global__ __launch_bounds__(64) void loss_mean(const float* __restrict__ ws_loss,
                                                float* __restrict__ out) {
  const float v = ws_loss[threadIdx.x];
  const float s = dpp_red_sum(v);
  if (threadIdx.x == 0) out[0] = s * (1.0f / 64.0f);
}

extern "C" void kernel_launch(void* const* d_in, const int* in_sizes, int n_in,
                              void* d_out, int out_size, void* d_ws, size_t ws_size,
                              hipStream_t stream) {
  const float* X = (const float*)d_in[0];
  const int* mask = (const int*)d_in[1];
  const int* labels = (const int*)d_in[2];
  const float* W = (const float*)d_in[3];
  const float* bias = (const float*)d_in[4];
  const float* trans = (const float*)d_in[5];
  const float* startv = (const float*)d_in[6];
  const float* endv = (const float*)d_in[7];

  float* out = (float*)d_out;
  float* scores = out;
  float* out_tags = out + TAGS_OFF;
  float* out_loss = out + LOSS_OFF;

  float* ws_loss = (float*)d_ws;  // 64 floats

  gemm_scores<<<512, 256, 0, stream>>>(X, mask, W, bias, scores);
  crf_forward<<<128, 256, 0, stream>>>(scores, mask, labels, trans, startv, endv,
                                       out_tags, ws_loss);
  loss_mean<<<1, 64, 0, stream>>>(ws_loss, out_loss);
}

// Round 8
// 555.512 us; speedup vs baseline: 1.2906x; 1.2906x over previous
//
#include <hip/hip_runtime.h>
#include <cstdint>
#include <cstddef>

#define BB 64
#define TT 512
#define DD 1024
#define NTAG 64
#define SCORES_ELEMS (BB * TT * NTAG)      // 2097152
#define TAGS_OFF SCORES_ELEMS              // 2097152
#define LOSS_OFF (SCORES_ELEMS + BB * TT)  // 2130920

typedef __attribute__((ext_vector_type(8))) short short8;
typedef __attribute__((ext_vector_type(4))) float floatx4;

__device__ __forceinline__ float rl(float v, int i) {
  return __int_as_float(__builtin_amdgcn_readlane(__float_as_int(v), i));
}

__device__ __forceinline__ unsigned short f2bf_rne(float x) {
  const unsigned int u = __float_as_uint(x);
  const unsigned int r = u + 0x7FFFu + ((u >> 16) & 1u);
  return (unsigned short)(r >> 16);
}
__device__ __forceinline__ float bf2f(unsigned short h) {
  return __uint_as_float(((unsigned int)h) << 16);
}

// ---------------- DPP wave64 reductions ----------------
__device__ __forceinline__ float dpp_red_max(float v) {
  int x;
  x = __builtin_amdgcn_update_dpp(__float_as_int(v), __float_as_int(v), 0x111, 0xf, 0xf, false);
  v = fmaxf(v, __int_as_float(x));
  x = __builtin_amdgcn_update_dpp(__float_as_int(v), __float_as_int(v), 0x112, 0xf, 0xf, false);
  v = fmaxf(v, __int_as_float(x));
  x = __builtin_amdgcn_update_dpp(__float_as_int(v), __float_as_int(v), 0x114, 0xf, 0xf, false);
  v = fmaxf(v, __int_as_float(x));
  x = __builtin_amdgcn_update_dpp(__float_as_int(v), __float_as_int(v), 0x118, 0xf, 0xf, false);
  v = fmaxf(v, __int_as_float(x));
  x = __builtin_amdgcn_update_dpp(__float_as_int(v), __float_as_int(v), 0x142, 0xa, 0xf, false);
  v = fmaxf(v, __int_as_float(x));
  x = __builtin_amdgcn_update_dpp(__float_as_int(v), __float_as_int(v), 0x143, 0xc, 0xf, false);
  v = fmaxf(v, __int_as_float(x));
  return __int_as_float(__builtin_amdgcn_readlane(__float_as_int(v), 63));
}

__device__ __forceinline__ float dpp_red_sum(float v) {
  int x;
  x = __builtin_amdgcn_update_dpp(__float_as_int(v), __float_as_int(v), 0x111, 0xf, 0xf, false);
  v = v + __int_as_float(x);
  x = __builtin_amdgcn_update_dpp(__float_as_int(v), __float_as_int(v), 0x112, 0xf, 0xf, false);
  v = v + __int_as_float(x);
  x = __builtin_amdgcn_update_dpp(__float_as_int(v), __float_as_int(v), 0x114, 0xf, 0xf, false);
  v = v + __int_as_float(x);
  x = __builtin_amdgcn_update_dpp(__float_as_int(v), __float_as_int(v), 0x118, 0xf, 0xf, false);
  v = v + __int_as_float(x);
  x = __builtin_amdgcn_update_dpp(__float_as_int(v), __float_as_int(v), 0x142, 0xa, 0xf, false);
  v = v + __int_as_float(x);
  x = __builtin_amdgcn_update_dpp(__float_as_int(v), __float_as_int(v), 0x143, 0xc, 0xf, false);
  v = v + __int_as_float(x);
  return __int_as_float(__builtin_amdgcn_readlane(__float_as_int(v), 63));
}

// ---------------- Kernel 0: W -> bf16 hi/lo fragments (B-operand order) ----
// Emits Wfrag[kk32][nt][lane][j] so the GEMM's B-frag loads are one fully
// coalesced 16B/lane read. B layout: B[k=(lane>>4)*8+j][n=nt*16+(lane&15)].
__global__ __launch_bounds__(256) void prep_w(
    const float* __restrict__ W, unsigned short* __restrict__ wf_hi,
    unsigned short* __restrict__ wf_lo) {
  const int f = blockIdx.x * 256 + threadIdx.x;  // 0..8191
  const int kk = f >> 8;
  const int nt = (f >> 6) & 3;
  const int l = f & 63;
  const int n = nt * 16 + (l & 15);
  const int k0 = kk * 32 + ((l >> 4) << 3);
  short8 hv, lv;
#pragma unroll
  for (int j = 0; j < 8; ++j) {
    const float x = W[(size_t)(k0 + j) * NTAG + n];
    const unsigned short h = f2bf_rne(x);
    hv[j] = (short)h;
    lv[j] = (short)f2bf_rne(x - bf2f(h));
  }
  *reinterpret_cast<short8*>(wf_hi + (size_t)f * 8) = hv;
  *reinterpret_cast<short8*>(wf_lo + (size_t)f * 8) = lv;
}

// ---------------- Kernel 1: scores = (X @ W + b) * mask  (MFMA) ----------
// 512 blocks x 256 thr. Block = 64 rows x 64 cols x K=1024 (16 chunks of 64k).
// fp32 split: X ~ hi+lo bf16; X@W ~ Xhi@Whi + Xhi@Wlo + Xlo@Whi (err ~1e-4).
// X staged+converted in LDS (A-frags); W frags direct from global (L2-hot,
// coalesced). Wave w computes rows [w*16,w*16+16) x all 64 cols: 4 acc tiles.
__global__ __launch_bounds__(256) void gemm_scores(
    const float* __restrict__ X, const int* __restrict__ mask,
    const unsigned short* __restrict__ wf_hi,
    const unsigned short* __restrict__ wf_lo,
    const float* __restrict__ bias, float* __restrict__ scores) {
  __shared__ unsigned short xhi[64 * 72];  // [row][k], stride 72 (144B, 16B-mult)
  __shared__ unsigned short xlo[64 * 72];
  const int tid = threadIdx.x;
  const int lane = tid & 63;
  const int wv = tid >> 6;
  const int row0 = blockIdx.x * 64;
  const int srow = tid >> 2;  // staging row 0..63
  const int scg = tid & 3;    // 16-col group
  const float* Xp = X + (size_t)(row0 + srow) * DD + scg * 16;

  floatx4 acc[4];
#pragma unroll
  for (int nt = 0; nt < 4; ++nt) acc[nt] = (floatx4)(0.f);

  float4 px[4];
#pragma unroll
  for (int p = 0; p < 4; ++p) px[p] = *reinterpret_cast<const float4*>(Xp + p * 4);

  const int arow = (wv << 4) + (lane & 15);
  const int aq = (lane >> 4) << 3;  // k sub-offset 0,8,16,24

  for (int c = 0; c < 16; ++c) {
    __syncthreads();  // prior chunk's readers done
    // convert 16 fp32 -> bf16 hi/lo, write as b128s
    short8 hb0, hb1, lb0, lb1;
#pragma unroll
    for (int p = 0; p < 4; ++p) {
      const float v[4] = {px[p].x, px[p].y, px[p].z, px[p].w};
#pragma unroll
      for (int e = 0; e < 4; ++e) {
        const unsigned short h = f2bf_rne(v[e]);
        const unsigned short lo2 = f2bf_rne(v[e] - bf2f(h));
        const int idx = p * 4 + e;
        if (idx < 8) { hb0[idx] = (short)h; lb0[idx] = (short)lo2; }
        else         { hb1[idx - 8] = (short)h; lb1[idx - 8] = (short)lo2; }
      }
    }
    {
      const int base = srow * 72 + scg * 16;
      *reinterpret_cast<short8*>(&xhi[base]) = hb0;
      *reinterpret_cast<short8*>(&xhi[base + 8]) = hb1;
      *reinterpret_cast<short8*>(&xlo[base]) = lb0;
      *reinterpret_cast<short8*>(&xlo[base + 8]) = lb1;
    }
    const int cn = (c < 15) ? (c + 1) : 0;  // dummy reload last iter
#pragma unroll
    for (int p = 0; p < 4; ++p)
      px[p] = *reinterpret_cast<const float4*>(Xp + cn * 64 + p * 4);
    __syncthreads();

#pragma unroll
    for (int sub = 0; sub < 2; ++sub) {
      const int kkAbs = c * 2 + sub;  // 32-k subchunk index
      const short8 ah = *reinterpret_cast<const short8*>(&xhi[arow * 72 + sub * 32 + aq]);
      const short8 al = *reinterpret_cast<const short8*>(&xlo[arow * 72 + sub * 32 + aq]);
      const size_t fbase = (size_t)kkAbs * 4 * 64 * 8;
#pragma unroll
      for (int nt = 0; nt < 4; ++nt) {
        const size_t off = fbase + ((size_t)nt * 64 + lane) * 8;
        const short8 bh = *reinterpret_cast<const short8*>(wf_hi + off);
        const short8 bl = *reinterpret_cast<const short8*>(wf_lo + off);
        acc[nt] = __builtin_amdgcn_mfma_f32_16x16x32_bf16(ah, bh, acc[nt], 0, 0, 0);
        acc[nt] = __builtin_amdgcn_mfma_f32_16x16x32_bf16(ah, bl, acc[nt], 0, 0, 0);
        acc[nt] = __builtin_amdgcn_mfma_f32_16x16x32_bf16(al, bh, acc[nt], 0, 0, 0);
      }
    }
  }

  // epilogue: C/D layout col=lane&15, row=(lane>>4)*4+reg
  const int colb = lane & 15;
  const int quad = lane >> 4;
#pragma unroll
  for (int r = 0; r < 4; ++r) {
    const int row = row0 + (wv << 4) + quad * 4 + r;
    const float mf = (float)mask[row];
#pragma unroll
    for (int nt = 0; nt < 4; ++nt) {
      const int col = nt * 16 + colb;
      scores[(size_t)row * 64 + col] = (acc[nt][r] + bias[col]) * mf;
    }
  }
}

// ---------------- Kernel 2: forward passes (single wave; readlane) --------
__global__ __launch_bounds__(64) void crf_forward(
    const float* __restrict__ scores, const int* __restrict__ mask,
    const int* __restrict__ labels, const float* __restrict__ trans,
    const float* __restrict__ startv, const float* __restrict__ endv,
    float* __restrict__ ws_alpha, int* __restrict__ ws_lasttag,
    float* __restrict__ ws_loss) {
  const int lane = threadIdx.x;
  const int role = blockIdx.x >> 6;
  const int b = blockIdx.x & 63;
  const float* sc = scores + (size_t)b * TT * NTAG;
  const int* maskb = mask + b * TT;

  if (role == 0) {
    float tcol[NTAG];  // tcol[i] = trans[i][lane]
#pragma unroll
    for (int i = 0; i < NTAG; ++i) tcol[i] = trans[(size_t)i * NTAG + lane];
    float valpha = startv[lane] + sc[lane];
    float* wsA = ws_alpha + (size_t)b * (TT - 1) * NTAG;

    float e0 = sc[1 * NTAG + lane], e1 = sc[2 * NTAG + lane];
    float e2 = sc[3 * NTAG + lane], e3 = sc[4 * NTAG + lane];
    int k0 = maskb[1], k1 = maskb[2], k2 = maskb[3], k3 = maskb[4];

    for (int t = 1; t < TT; ++t) {
      wsA[(size_t)(t - 1) * NTAG + lane] = valpha;
      const float emit = e0;
      const int m = k0;
      const int tp = (t + 4 < TT) ? (t + 4) : (TT - 1);
      e0 = e1; e1 = e2; e2 = e3;
      e3 = sc[(size_t)tp * NTAG + lane];
      k0 = k1; k1 = k2; k2 = k3;
      k3 = maskb[tp];

      float m0 = -3.4e38f, m1 = -3.4e38f, m2 = -3.4e38f, m3 = -3.4e38f;
#pragma unroll
      for (int i = 0; i < NTAG; i += 4) {
        m0 = fmaxf(m0, rl(valpha, i + 0) + tcol[i + 0]);
        m1 = fmaxf(m1, rl(valpha, i + 1) + tcol[i + 1]);
        m2 = fmaxf(m2, rl(valpha, i + 2) + tcol[i + 2]);
        m3 = fmaxf(m3, rl(valpha, i + 3) + tcol[i + 3]);
      }
      const float best = fmaxf(fmaxf(m0, m1), fmaxf(m2, m3));
      valpha = m ? (best + emit) : valpha;
    }

    const float fin = valpha + endv[lane];
    const float mx = dpp_red_max(fin);
    const int jlast = (int)__builtin_ctzll(__ballot(fin == mx));
    if (lane == 0) ws_lasttag[b] = jlast;
  } else {
    float ecol[NTAG];  // exp(trans[i][lane])
#pragma unroll
    for (int i = 0; i < NTAG; ++i) ecol[i] = expf(trans[(size_t)i * NTAG + lane]);

    const float alpha0 = startv[lane] + sc[lane];
    const float M0 = dpp_red_max(alpha0);
    float z = expf(alpha0 - M0);  // z = exp(alpha - C)
    float C = M0;

    float e0 = sc[1 * NTAG + lane], e1 = sc[2 * NTAG + lane];
    float e2 = sc[3 * NTAG + lane], e3 = sc[4 * NTAG + lane];
    int k0 = maskb[1], k1 = maskb[2], k2 = maskb[3], k3 = maskb[4];
    float pe = expf(e0);

    for (int t = 1; t < TT; ++t) {
      const float pec = pe;
      const int m = k0;
      const int tp = (t + 4 < TT) ? (t + 4) : (TT - 1);
      e0 = e1; e1 = e2; e2 = e3;
      e3 = sc[(size_t)tp * NTAG + lane];
      k0 = k1; k1 = k2; k2 = k3;
      k3 = maskb[tp];
      pe = expf(e0);  // off critical path

      float s0 = 0.f, s1 = 0.f, s2 = 0.f, s3 = 0.f;
#pragma unroll
      for (int i = 0; i < NTAG; i += 4) {
        s0 = fmaf(rl(z, i + 0), ecol[i + 0], s0);
        s1 = fmaf(rl(z, i + 1), ecol[i + 1], s1);
        s2 = fmaf(rl(z, i + 2), ecol[i + 2], s2);
        s3 = fmaf(rl(z, i + 3), ecol[i + 3], s3);
      }
      const float inner = (s0 + s1) + (s2 + s3);
      z = m ? (inner * pec) : z;

      if ((t & 7) == 0) {  // renormalize; growth bounded, fp32-safe
        const float s = dpp_red_sum(z);
        const float r = __builtin_amdgcn_rcpf(s);
        z *= r;
        C += logf(s);
      }
    }
    const float av = logf(z) + C;
    const float fv = av + endv[lane];
    const float M2 = dpp_red_max(fv);
    const float sSum = dpp_red_sum(expf(fv - M2));
    const float log_z = logf(sSum) + M2;

    float g = 0.f, msumf = 0.f;
    for (int t = lane; t < TT; t += 64) {
      const int lab = labels[b * TT + t];
      const float mf = (float)maskb[t];
      msumf += mf;
      g += sc[(size_t)t * NTAG + lab] * mf;
      if (t >= 1) {
        const int labp = labels[b * TT + t - 1];
        g += trans[(size_t)labp * NTAG + lab] * mf;
      }
    }
    g = dpp_red_sum(g);
    const float msum = dpp_red_sum(msumf);
    const int last_idx = (int)msum - 1;
    g += startv[labels[b * TT]] + endv[labels[b * TT + last_idx]];
    if (lane == 0) ws_loss[b] = log_z - g;
  }
}

// ---------------- Kernel 3: backtrack via on-the-fly recompute ----------
__global__ __launch_bounds__(64) void viterbi_bt(
    const float* __restrict__ ws_alpha, const int* __restrict__ ws_lasttag,
    const int* __restrict__ mask, const float* __restrict__ trans,
    float* __restrict__ out_tags) {
  __shared__ float tP[NTAG * 65];  // tP[i*65+j] = trans[i][j]
  __shared__ int mk[TT];
  __shared__ unsigned char tagb[TT];
  const int lane = threadIdx.x;
  const int b = blockIdx.x;

#pragma unroll
  for (int i = 0; i < NTAG; ++i) tP[i * 65 + lane] = trans[(size_t)i * NTAG + lane];
  for (int t = lane; t < TT; t += 64) mk[t] = mask[b * TT + t];

  const float* wsA = ws_alpha + (size_t)b * (TT - 1) * NTAG;
  int jcur = ws_lasttag[b];
  if (lane == 0) tagb[TT - 1] = (unsigned char)jcur;

  float a0 = wsA[(size_t)(TT - 2) * NTAG + lane];
  float a1 = wsA[(size_t)(TT - 3) * NTAG + lane];
  float a2 = wsA[(size_t)(TT - 4) * NTAG + lane];
  float a3 = wsA[(size_t)(TT - 5) * NTAG + lane];

  for (int s = TT - 2; s >= 0; --s) {
    const float ac = a0;  // alpha_s
    a0 = a1; a1 = a2; a2 = a3;
    const int sp = (s >= 4) ? (s - 4) : 0;  // regs held {s..s-3}; refill s-4
    a3 = wsA[(size_t)sp * NTAG + lane];
    if (mk[s + 1]) {
      const float c = ac + tP[lane * 65 + jcur];
      const float cmx = dpp_red_max(c);
      jcur = (int)__builtin_ctzll(__ballot(c == cmx));
    }
    if (lane == 0) tagb[s] = (unsigned char)jcur;
  }

  for (int t = lane; t < TT; t += 64)
    out_tags[b * TT + t] = (float)(mk[t] ? (int)tagb[t] : 0);
}

// ---------------- Kernel 4: loss = mean(log_z - gold) ----------------
__global__ __launch_bounds__(64) void loss_mean(const float* __restrict__ ws_loss,
                                                float* __restrict__ out) {
  const float v = ws_loss[threadIdx.x];
  const float s = dpp_red_sum(v);
  if (threadIdx.x == 0) out[0] = s * (1.0f / 64.0f);
}

extern "C" void kernel_launch(void* const* d_in, const int* in_sizes, int n_in,
                              void* d_out, int out_size, void* d_ws, size_t ws_size,
                              hipStream_t stream) {
  const float* X = (const float*)d_in[0];
  const int* mask = (const int*)d_in[1];
  const int* labels = (const int*)d_in[2];
  const float* W = (const float*)d_in[3];
  const float* bias = (const float*)d_in[4];
  const float* trans = (const float*)d_in[5];
  const float* startv = (const float*)d_in[6];
  const float* endv = (const float*)d_in[7];

  float* out = (float*)d_out;
  float* scores = out;
  float* out_tags = out + TAGS_OFF;
  float* out_loss = out + LOSS_OFF;

  unsigned short* wf_hi = (unsigned short*)d_ws;        // 65536 bf16
  unsigned short* wf_lo = wf_hi + 65536;                // 65536 bf16
  float* ws_alpha = (float*)(wf_lo + 65536);            // 64*511*64 fp32
  int* ws_lasttag = (int*)(ws_alpha + (size_t)BB * (TT - 1) * NTAG);
  float* ws_loss = (float*)(ws_lasttag + BB);

  prep_w<<<32, 256, 0, stream>>>(W, wf_hi, wf_lo);
  gemm_scores<<<512, 256, 0, stream>>>(X, mask, wf_hi, wf_lo, bias, scores);
  crf_forward<<<128, 64, 0, stream>>>(scores, mask, labels, trans, startv, endv,
                                      ws_alpha, ws_lasttag, ws_loss);
  viterbi_bt<<<64, 64, 0, stream>>>(ws_alpha, ws_lasttag, mask, trans, out_tags);
  loss_mean<<<1, 64, 0, stream>>>(ws_loss, out_loss);
}